// Round 9
// baseline (18.861 us; speedup 1.0000x reference)
//
#include <hip/hip_runtime.h>

// Forward output of the reference == hard top-k0 binary mask (straight-through
// (hard-soft)+soft == hard exactly in fp32; top-k0 set of soft == top-k0 set
// of x since clip(x+nu) is monotone). Tie-break for exact fp32 duplicates:
// lowest index first (matches jax.lax.top_k).
//
// Kernel == round-5 best (11.95 us): one 512-thread block (8 waves) per row,
// 8 keys/lane in registers; 2 histogram passes fix the top-16-bit prefix
// (pass-0 into 16 replicated copies; hot byte = sign|exp[7:1] holds ~29% of
// N(0,1) -> same-address LDS atomic serialization without replicas);
// survivors (T ~ 4) finish with a 16-step ballot bit-select, redundant in all
// waves. Histogram fallback for T > 64 keeps it exact.
//
// DIAGNOSTIC THIS ROUND: kernel launched TWICE (second writes the same mask
// to d_ws scratch; d_out if ws too small). dur_us delta vs r5 == true kernel
// HW time, discriminating "replay-overhead floor" vs "real 10us kernel".

#define DIM  4096
#define EPL  8              // elems per lane: 8 waves * 64 lanes * 8 = 4096
#define NC0  16             // pass-0 histogram replicas
#define CPAD 260            // replica stride (ints): 16B-aligned, bank-shifted

__device__ __forceinline__ void select_bin(const int4 h, const int lane, const int kr,
                                           int& chosen, int& cumG, int& T) {
    // h = this lane's 4 bins (bins 4*lane .. 4*lane+3). Finds bin containing
    // the kr-th largest, count strictly greater (cumG), and bin count (T).
    const int s3 = h.w, s2 = h.z + s3, s1 = h.y + s2, s0 = h.x + s1;
    int v = s0;
    #pragma unroll
    for (int off = 1; off < 64; off <<= 1) {
        int t = __shfl_down(v, off, 64);
        if (lane + off < 64) v += t;
    }
    const int inc = v - s0;                       // totals of lanes > l
    const int S0 = s0 + inc, S1 = s1 + inc, S2 = s2 + inc, S3 = s3 + inc;
    int ci, cg, Tl;
    if      (S3 >= kr) { ci = 3; cg = inc; Tl = h.w; }
    else if (S2 >= kr) { ci = 2; cg = S3;  Tl = h.z; }
    else if (S1 >= kr) { ci = 1; cg = S2;  Tl = h.y; }
    else               { ci = 0; cg = S1;  Tl = h.x; }
    const bool has = (S0 >= kr) && (inc < kr);    // exactly one lane true
    const unsigned long long m = __ballot(has);
    const int src = __ffsll((unsigned long long)m) - 1;
    chosen = __shfl((lane << 2) + ci, src, 64);
    cumG   = __shfl(cg, src, 64);
    T      = __shfl(Tl, src, 64);
}

__global__ void __launch_bounds__(512)
topk_mask_kernel(const float* __restrict__ x, const int* __restrict__ k0ptr,
                 float* __restrict__ out) {
    const int tid  = threadIdx.x;
    const int lane = tid & 63;
    const int w    = tid >> 6;                    // 0..7
    const int row  = blockIdx.x;

    const float4* xr4   = (const float4*)(x   + (size_t)row * DIM);
    float4*       outr4 = (float4*)      (out + (size_t)row * DIM);

    __shared__ int hist0[NC0 * CPAD];             // pass-0 replicas
    __shared__ int histp[3][256];                 // pass 1 + fallback passes
    __shared__ unsigned int surv[64];
    __shared__ int scnt;
    __shared__ int wtie[8];

    const int k0 = k0ptr[0];                      // early uniform load

    // Wave w owns elements [512w, 512w+512); elem of u[4i+c] (i in 0..1) is
    // 512w + 256i + 4*lane + c -> lexicographic (w,i,lane,c) = ascending idx.
    const float4 f0 = xr4[(w << 7) + lane];
    const float4 f1 = xr4[(w << 7) + 64 + lane];

    // Zero LDS while loads are in flight.
    for (int t = tid; t < NC0 * CPAD; t += 512) hist0[t] = 0;
    for (int t = tid; t < 3 * 256;   t += 512) ((int*)histp)[t] = 0;
    if (tid == 0) scnt = 0;

    // fp32 -> sortable-ascending uint32 (registers, static indexing).
    unsigned int u[EPL];
#define MAP4(i, vv)                                                        \
    {                                                                      \
        unsigned int b0 = __float_as_uint((vv).x);                         \
        unsigned int b1 = __float_as_uint((vv).y);                         \
        unsigned int b2 = __float_as_uint((vv).z);                         \
        unsigned int b3 = __float_as_uint((vv).w);                         \
        u[4*(i)+0] = (b0 & 0x80000000u) ? ~b0 : (b0 | 0x80000000u);        \
        u[4*(i)+1] = (b1 & 0x80000000u) ? ~b1 : (b1 | 0x80000000u);        \
        u[4*(i)+2] = (b2 & 0x80000000u) ? ~b2 : (b2 | 0x80000000u);        \
        u[4*(i)+3] = (b3 & 0x80000000u) ? ~b3 : (b3 | 0x80000000u);        \
    }
    MAP4(0, f0) MAP4(1, f1)
#undef MAP4

    __syncthreads();                              // zeros visible

    // ---- pass 0: replicated histogram of top byte ----
    const int c0 = ((((w & 1) << 3) | (lane & 7))) * CPAD;
    #pragma unroll
    for (int j = 0; j < EPL; ++j)
        atomicAdd(&hist0[c0 + (u[j] >> 24)], 1);
    __syncthreads();

    int kr = k0;
    int4 h; h.x = 0; h.y = 0; h.z = 0; h.w = 0;
    #pragma unroll
    for (int c = 0; c < NC0; ++c) {
        const int4 t = *(const int4*)&hist0[c * CPAD + (lane << 2)];
        h.x += t.x; h.y += t.y; h.z += t.z; h.w += t.w;
    }
    int chosen, cumG, T;
    select_bin(h, lane, kr, chosen, cumG, T);
    kr -= cumG;
    unsigned int pfx = ((unsigned int)chosen) << 24;

    // ---- pass 1: byte 2 among survivors (sparse -> single copy) ----
    #pragma unroll
    for (int j = 0; j < EPL; ++j)
        if ((u[j] >> 24) == (pfx >> 24))
            atomicAdd(&histp[0][(u[j] >> 16) & 255u], 1);
    __syncthreads();
    h = *(const int4*)&histp[0][lane << 2];
    select_bin(h, lane, kr, chosen, cumG, T);
    kr -= cumG;
    pfx |= ((unsigned int)chosen) << 16;

    unsigned int thr;
    if (T <= 64) {
        // ---- common path: compact survivors, ballot bit-select low 16 bits --
        #pragma unroll
        for (int j = 0; j < EPL; ++j)
            if ((u[j] & 0xFFFF0000u) == pfx) {
                const int slot = atomicAdd(&scnt, 1);
                surv[slot] = u[j];
            }
        __syncthreads();
        // Every wave runs this redundantly on identical data -> no broadcast.
        const unsigned int v = (lane < T) ? surv[lane] : 0u;
        bool act = (lane < T);
        #pragma unroll
        for (int b = 15; b >= 0; --b) {
            const unsigned int bit = (v >> b) & 1u;
            const unsigned long long m1 = __ballot(act && (bit != 0u));
            const int c = __popcll(m1);
            const bool ge = (c >= kr);
            act = act && (bit == (ge ? 1u : 0u));
            if (!ge) kr -= c;
        }
        const unsigned long long ma = __ballot(act);
        T   = __popcll(ma);
        thr = __shfl(v, __ffsll((unsigned long long)ma) - 1, 64);
    } else {
        // ---- fallback: histogram passes for bytes 1 and 0 ----
        #pragma unroll
        for (int j = 0; j < EPL; ++j)
            if ((u[j] & 0xFFFF0000u) == pfx)
                atomicAdd(&histp[1][(u[j] >> 8) & 255u], 1);
        __syncthreads();
        h = *(const int4*)&histp[1][lane << 2];
        select_bin(h, lane, kr, chosen, cumG, T);
        kr -= cumG;
        pfx |= ((unsigned int)chosen) << 8;

        #pragma unroll
        for (int j = 0; j < EPL; ++j)
            if ((u[j] & 0xFFFFFF00u) == pfx)
                atomicAdd(&histp[2][u[j] & 255u], 1);
        __syncthreads();
        h = *(const int4*)&histp[2][lane << 2];
        select_bin(h, lane, kr, chosen, cumG, T);
        kr -= cumG;
        thr = pfx | (unsigned int)chosen;
    }
    // thr = k-th largest key; kr = ties to select; T = total ties (uniform).

    if (kr == T) {
        // All threshold ties selected: pure >= mask from registers.
        #pragma unroll
        for (int i = 0; i < 2; ++i) {
            float4 o;
            o.x = (u[4*i+0] >= thr) ? 1.0f : 0.0f;
            o.y = (u[4*i+1] >= thr) ? 1.0f : 0.0f;
            o.z = (u[4*i+2] >= thr) ? 1.0f : 0.0f;
            o.w = (u[4*i+3] >= thr) ? 1.0f : 0.0f;
            outr4[(w << 7) + (i << 6) + lane] = o;
        }
    } else {
        // Rare: rank exact ties in ascending global index order.
        int eqtot = 0;
        #pragma unroll
        for (int j = 0; j < EPL; ++j) eqtot += (u[j] == thr) ? 1 : 0;
        int vv = eqtot;
        #pragma unroll
        for (int off = 1; off < 64; off <<= 1) {
            int t = __shfl_up(vv, off, 64);
            if (lane >= off) vv += t;
        }
        if (lane == 63) wtie[w] = vv;             // per-wave tie totals
        __syncthreads();
        int base = 0;
        #pragma unroll
        for (int ww = 0; ww < 8; ++ww) if (ww < w) base += wtie[ww];

        #pragma unroll
        for (int i = 0; i < 2; ++i) {
            const int e0 = (u[4*i+0] == thr) ? 1 : 0;
            const int e1 = (u[4*i+1] == thr) ? 1 : 0;
            const int e2 = (u[4*i+2] == thr) ? 1 : 0;
            const int e3 = (u[4*i+3] == thr) ? 1 : 0;
            const int ti = e0 + e1 + e2 + e3;
            int vi = ti;
            #pragma unroll
            for (int off = 1; off < 64; off <<= 1) {
                int t = __shfl_up(vi, off, 64);
                if (lane >= off) vi += t;
            }
            int r = base + (vi - ti);             // ties before my first one
            const int tot = __shfl(vi, 63, 64);   // wave ties in this i-group
            float4 o;
            o.x = (u[4*i+0] > thr) ? 1.0f : ((e0 && r < kr) ? 1.0f : 0.0f); r += e0;
            o.y = (u[4*i+1] > thr) ? 1.0f : ((e1 && r < kr) ? 1.0f : 0.0f); r += e1;
            o.z = (u[4*i+2] > thr) ? 1.0f : ((e2 && r < kr) ? 1.0f : 0.0f); r += e2;
            o.w = (u[4*i+3] > thr) ? 1.0f : ((e3 && r < kr) ? 1.0f : 0.0f); r += e3;
            outr4[(w << 7) + (i << 6) + lane] = o;
            base += tot;
        }
    }
}

extern "C" void kernel_launch(void* const* d_in, const int* in_sizes, int n_in,
                              void* d_out, int out_size, void* d_ws, size_t ws_size,
                              hipStream_t stream) {
    const float* x   = (const float*)d_in[0];
    // d_in[1] = k vector [bs] (unused: forward mask depends only on k0)
    const int*   k0  = (const int*)d_in[2];
    float*       out = (float*)d_out;

    const int bs = in_sizes[1];                   // dim == 4096 (reference)

    // Launch 1: the real output.
    topk_mask_kernel<<<bs, 512, 0, stream>>>(x, k0, out);

    // Launch 2 (diagnostic): identical workload to scratch (or redundantly to
    // d_out if ws is too small). Deterministic; measures true kernel HW time
    // via the dur_us delta vs the single-launch round.
    float* out2 = (ws_size >= (size_t)bs * DIM * sizeof(float)) ? (float*)d_ws : out;
    topk_mask_kernel<<<bs, 512, 0, stream>>>(x, k0, out2);
}

// Round 10
// 11.522 us; speedup vs baseline: 1.6369x; 1.6369x over previous
//
#include <hip/hip_runtime.h>

// Forward output of the reference == hard top-k0 binary mask (straight-through
// (hard-soft)+soft == hard exactly in fp32; top-k0 set of soft == top-k0 set
// of x since clip(x+nu) is monotone). Tie-break for exact fp32 duplicates:
// lowest index first (matches jax.lax.top_k).
//
// One 512-thread block (8 waves) per row; 8 keys/lane in registers.
// Radix select: 2 histogram passes (8 bits each) fix the top-16-bit prefix;
// survivors (T ~ 4 for random data) are compacted and finished with a 16-step
// ballot bit-select run redundantly in all waves. Histogram fallback for
// T > 64 keeps it exact. Pass-0 histogram -> 16 replicated copies (hot byte =
// sign|exp[7:1] holds ~29% of N(0,1): same-address LDS atomic serialization
// without replicas).
//
// vs r5: (1) zero-LDS BEFORE the barrier, loads AFTER it -- __syncthreads
// drains vmcnt(0), so r5's order stalled all 8 waves on HBM latency in
// lockstep; now the barrier is cheap and waves de-sync into the atomics.
// (2) non-temporal stores (write-once output, no L3 dirty-allocate).
// (3) fallback histograms zeroed lazily inside the fallback branch.

#define DIM  4096
#define EPL  8              // elems per lane: 8 waves * 64 lanes * 8 = 4096
#define NC0  16             // pass-0 histogram replicas
#define CPAD 260            // replica stride (ints): 16B-aligned, bank-shifted

typedef float nfloat4 __attribute__((ext_vector_type(4)));

__device__ __forceinline__ void nt_store4(float4* p, const float4 o) {
    nfloat4 n; n.x = o.x; n.y = o.y; n.z = o.z; n.w = o.w;
    __builtin_nontemporal_store(n, (nfloat4*)p);
}

__device__ __forceinline__ void select_bin(const int4 h, const int lane, const int kr,
                                           int& chosen, int& cumG, int& T) {
    // h = this lane's 4 bins (bins 4*lane .. 4*lane+3). Finds bin containing
    // the kr-th largest, count strictly greater (cumG), and bin count (T).
    const int s3 = h.w, s2 = h.z + s3, s1 = h.y + s2, s0 = h.x + s1;
    int v = s0;
    #pragma unroll
    for (int off = 1; off < 64; off <<= 1) {
        int t = __shfl_down(v, off, 64);
        if (lane + off < 64) v += t;
    }
    const int inc = v - s0;                       // totals of lanes > l
    const int S0 = s0 + inc, S1 = s1 + inc, S2 = s2 + inc, S3 = s3 + inc;
    int ci, cg, Tl;
    if      (S3 >= kr) { ci = 3; cg = inc; Tl = h.w; }
    else if (S2 >= kr) { ci = 2; cg = S3;  Tl = h.z; }
    else if (S1 >= kr) { ci = 1; cg = S2;  Tl = h.y; }
    else               { ci = 0; cg = S1;  Tl = h.x; }
    const bool has = (S0 >= kr) && (inc < kr);    // exactly one lane true
    const unsigned long long m = __ballot(has);
    const int src = __ffsll((unsigned long long)m) - 1;
    chosen = __shfl((lane << 2) + ci, src, 64);
    cumG   = __shfl(cg, src, 64);
    T      = __shfl(Tl, src, 64);
}

__global__ void __launch_bounds__(512)
topk_mask_kernel(const float* __restrict__ x, const int* __restrict__ k0ptr,
                 float* __restrict__ out) {
    const int tid  = threadIdx.x;
    const int lane = tid & 63;
    const int w    = tid >> 6;                    // 0..7
    const int row  = blockIdx.x;

    const float4* xr4   = (const float4*)(x   + (size_t)row * DIM);
    float4*       outr4 = (float4*)      (out + (size_t)row * DIM);

    __shared__ int hist0[NC0 * CPAD];             // pass-0 replicas
    __shared__ int hist1[256];                    // pass 1
    __shared__ int histf[2][256];                 // fallback (lazily zeroed)
    __shared__ unsigned int surv[64];
    __shared__ int scnt;
    __shared__ int wtie[8];

    // ---- zero LDS FIRST: the upcoming barrier stays cheap (no vmcnt drain
    // of pending x loads, since none are issued yet).
    for (int t = tid; t < NC0 * CPAD; t += 512) hist0[t] = 0;
    if (tid < 256) hist1[tid] = 0;
    if (tid == 0) scnt = 0;
    __syncthreads();                              // zeros visible

    const int k0 = k0ptr[0];                      // uniform scalar load

    // ---- loads AFTER the barrier: each wave proceeds as ITS data arrives
    // (waves de-sync -> pass-0 atomic bursts spread in time).
    // Wave w owns elements [512w, 512w+512); elem of u[4i+c] (i in 0..1) is
    // 512w + 256i + 4*lane + c -> lexicographic (w,i,lane,c) = ascending idx.
    const float4 f0 = xr4[(w << 7) + lane];
    const float4 f1 = xr4[(w << 7) + 64 + lane];

    // fp32 -> sortable-ascending uint32 (registers, static indexing).
    unsigned int u[EPL];
#define MAP4(i, vv)                                                        \
    {                                                                      \
        unsigned int b0 = __float_as_uint((vv).x);                         \
        unsigned int b1 = __float_as_uint((vv).y);                         \
        unsigned int b2 = __float_as_uint((vv).z);                         \
        unsigned int b3 = __float_as_uint((vv).w);                         \
        u[4*(i)+0] = (b0 & 0x80000000u) ? ~b0 : (b0 | 0x80000000u);        \
        u[4*(i)+1] = (b1 & 0x80000000u) ? ~b1 : (b1 | 0x80000000u);        \
        u[4*(i)+2] = (b2 & 0x80000000u) ? ~b2 : (b2 | 0x80000000u);        \
        u[4*(i)+3] = (b3 & 0x80000000u) ? ~b3 : (b3 | 0x80000000u);        \
    }
    MAP4(0, f0) MAP4(1, f1)
#undef MAP4

    // ---- pass 0: replicated histogram of top byte ----
    const int c0 = ((((w & 1) << 3) | (lane & 7))) * CPAD;
    #pragma unroll
    for (int j = 0; j < EPL; ++j)
        atomicAdd(&hist0[c0 + (u[j] >> 24)], 1);
    __syncthreads();

    int kr = k0;
    int4 h; h.x = 0; h.y = 0; h.z = 0; h.w = 0;
    #pragma unroll
    for (int c = 0; c < NC0; ++c) {
        const int4 t = *(const int4*)&hist0[c * CPAD + (lane << 2)];
        h.x += t.x; h.y += t.y; h.z += t.z; h.w += t.w;
    }
    int chosen, cumG, T;
    select_bin(h, lane, kr, chosen, cumG, T);
    kr -= cumG;
    unsigned int pfx = ((unsigned int)chosen) << 24;

    // ---- pass 1: byte 2 among survivors (sparse -> single copy) ----
    #pragma unroll
    for (int j = 0; j < EPL; ++j)
        if ((u[j] >> 24) == (pfx >> 24))
            atomicAdd(&hist1[(u[j] >> 16) & 255u], 1);
    __syncthreads();
    h = *(const int4*)&hist1[lane << 2];
    select_bin(h, lane, kr, chosen, cumG, T);
    kr -= cumG;
    pfx |= ((unsigned int)chosen) << 16;

    unsigned int thr;
    if (T <= 64) {
        // ---- common path: compact survivors, ballot bit-select low 16 bits --
        #pragma unroll
        for (int j = 0; j < EPL; ++j)
            if ((u[j] & 0xFFFF0000u) == pfx) {
                const int slot = atomicAdd(&scnt, 1);
                surv[slot] = u[j];
            }
        __syncthreads();
        // Every wave runs this redundantly on identical data -> no broadcast.
        const unsigned int v = (lane < T) ? surv[lane] : 0u;
        bool act = (lane < T);
        #pragma unroll
        for (int b = 15; b >= 0; --b) {
            const unsigned int bit = (v >> b) & 1u;
            const unsigned long long m1 = __ballot(act && (bit != 0u));
            const int c = __popcll(m1);
            const bool ge = (c >= kr);
            act = act && (bit == (ge ? 1u : 0u));
            if (!ge) kr -= c;
        }
        const unsigned long long ma = __ballot(act);
        T   = __popcll(ma);
        thr = __shfl(v, __ffsll((unsigned long long)ma) - 1, 64);
    } else {
        // ---- fallback (adversarial tie mass): zero lazily, then histogram
        // passes for bytes 1 and 0 ----
        ((int*)histf)[tid] = 0;                   // 512 ints, 512 threads
        __syncthreads();
        #pragma unroll
        for (int j = 0; j < EPL; ++j)
            if ((u[j] & 0xFFFF0000u) == pfx)
                atomicAdd(&histf[0][(u[j] >> 8) & 255u], 1);
        __syncthreads();
        h = *(const int4*)&histf[0][lane << 2];
        select_bin(h, lane, kr, chosen, cumG, T);
        kr -= cumG;
        pfx |= ((unsigned int)chosen) << 8;

        #pragma unroll
        for (int j = 0; j < EPL; ++j)
            if ((u[j] & 0xFFFFFF00u) == pfx)
                atomicAdd(&histf[1][u[j] & 255u], 1);
        __syncthreads();
        h = *(const int4*)&histf[1][lane << 2];
        select_bin(h, lane, kr, chosen, cumG, T);
        kr -= cumG;
        thr = pfx | (unsigned int)chosen;
    }
    // thr = k-th largest key; kr = ties to select; T = total ties (uniform).

    if (kr == T) {
        // All threshold ties selected: pure >= mask from registers.
        #pragma unroll
        for (int i = 0; i < 2; ++i) {
            float4 o;
            o.x = (u[4*i+0] >= thr) ? 1.0f : 0.0f;
            o.y = (u[4*i+1] >= thr) ? 1.0f : 0.0f;
            o.z = (u[4*i+2] >= thr) ? 1.0f : 0.0f;
            o.w = (u[4*i+3] >= thr) ? 1.0f : 0.0f;
            nt_store4(&outr4[(w << 7) + (i << 6) + lane], o);
        }
    } else {
        // Rare: rank exact ties in ascending global index order.
        int eqtot = 0;
        #pragma unroll
        for (int j = 0; j < EPL; ++j) eqtot += (u[j] == thr) ? 1 : 0;
        int vv = eqtot;
        #pragma unroll
        for (int off = 1; off < 64; off <<= 1) {
            int t = __shfl_up(vv, off, 64);
            if (lane >= off) vv += t;
        }
        if (lane == 63) wtie[w] = vv;             // per-wave tie totals
        __syncthreads();
        int base = 0;
        #pragma unroll
        for (int ww = 0; ww < 8; ++ww) if (ww < w) base += wtie[ww];

        #pragma unroll
        for (int i = 0; i < 2; ++i) {
            const int e0 = (u[4*i+0] == thr) ? 1 : 0;
            const int e1 = (u[4*i+1] == thr) ? 1 : 0;
            const int e2 = (u[4*i+2] == thr) ? 1 : 0;
            const int e3 = (u[4*i+3] == thr) ? 1 : 0;
            const int ti = e0 + e1 + e2 + e3;
            int vi = ti;
            #pragma unroll
            for (int off = 1; off < 64; off <<= 1) {
                int t = __shfl_up(vi, off, 64);
                if (lane >= off) vi += t;
            }
            int r = base + (vi - ti);             // ties before my first one
            const int tot = __shfl(vi, 63, 64);   // wave ties in this i-group
            float4 o;
            o.x = (u[4*i+0] > thr) ? 1.0f : ((e0 && r < kr) ? 1.0f : 0.0f); r += e0;
            o.y = (u[4*i+1] > thr) ? 1.0f : ((e1 && r < kr) ? 1.0f : 0.0f); r += e1;
            o.z = (u[4*i+2] > thr) ? 1.0f : ((e2 && r < kr) ? 1.0f : 0.0f); r += e2;
            o.w = (u[4*i+3] > thr) ? 1.0f : ((e3 && r < kr) ? 1.0f : 0.0f); r += e3;
            nt_store4(&outr4[(w << 7) + (i << 6) + lane], o);
            base += tot;
        }
    }
}

extern "C" void kernel_launch(void* const* d_in, const int* in_sizes, int n_in,
                              void* d_out, int out_size, void* d_ws, size_t ws_size,
                              hipStream_t stream) {
    const float* x   = (const float*)d_in[0];
    // d_in[1] = k vector [bs] (unused: forward mask depends only on k0)
    const int*   k0  = (const int*)d_in[2];
    float*       out = (float*)d_out;

    const int bs = in_sizes[1];                   // dim == 4096 (reference)
    topk_mask_kernel<<<bs, 512, 0, stream>>>(x, k0, out);
}

// Round 11
// 11.337 us; speedup vs baseline: 1.6638x; 1.0164x over previous
//
#include <hip/hip_runtime.h>

// Forward output of the reference == hard top-k0 binary mask (straight-through
// (hard-soft)+soft == hard exactly in fp32; top-k0 set of soft == top-k0 set
// of x since clip(x+nu) is monotone). Tie-break for exact fp32 duplicates:
// lowest index first (matches jax.lax.top_k).
//
// One 512-thread block (8 waves) per row; 8 keys/lane in registers.
// Radix select: 2 histogram passes (8 bits each) fix the top-16-bit prefix;
// survivors (T ~ 4 for random data) are compacted and finished with a 16-step
// ballot bit-select run redundantly in all waves. Histogram fallback for
// T > 64 keeps it exact. Pass-0 histogram -> 8 replicated copies keyed lane&7
// (hot byte = sign|exp[7:1] holds ~29% of N(0,1): same-address LDS atomic
// serialization without replicas; replica bases land on 8 distinct banks via
// stride-260 layout).
//
// vs r10: NC0 16 -> 8 (the all-wave redundant replica merge was the largest
// non-memory cost: 128 ds_read_b128 wave-inst/row through the single per-CU
// LDS pipe ~= 0.85 us/CU; halving replicas halves it, contention per
// instruction stays ~2.3 hot lanes/replica) + non-temporal x loads (read-once
// per replay; skip L3 allocate churn, matching the nt stores).

#define DIM  4096
#define EPL  8              // elems per lane: 8 waves * 64 lanes * 8 = 4096
#define NC0  8              // pass-0 histogram replicas
#define CPAD 260            // replica stride (ints): 16B-aligned, bank-shifted

typedef float nfloat4 __attribute__((ext_vector_type(4)));

__device__ __forceinline__ void nt_store4(float4* p, const float4 o) {
    nfloat4 n; n.x = o.x; n.y = o.y; n.z = o.z; n.w = o.w;
    __builtin_nontemporal_store(n, (nfloat4*)p);
}

__device__ __forceinline__ nfloat4 nt_load4(const float4* p) {
    return __builtin_nontemporal_load((const nfloat4*)p);
}

__device__ __forceinline__ void select_bin(const int4 h, const int lane, const int kr,
                                           int& chosen, int& cumG, int& T) {
    // h = this lane's 4 bins (bins 4*lane .. 4*lane+3). Finds bin containing
    // the kr-th largest, count strictly greater (cumG), and bin count (T).
    const int s3 = h.w, s2 = h.z + s3, s1 = h.y + s2, s0 = h.x + s1;
    int v = s0;
    #pragma unroll
    for (int off = 1; off < 64; off <<= 1) {
        int t = __shfl_down(v, off, 64);
        if (lane + off < 64) v += t;
    }
    const int inc = v - s0;                       // totals of lanes > l
    const int S0 = s0 + inc, S1 = s1 + inc, S2 = s2 + inc, S3 = s3 + inc;
    int ci, cg, Tl;
    if      (S3 >= kr) { ci = 3; cg = inc; Tl = h.w; }
    else if (S2 >= kr) { ci = 2; cg = S3;  Tl = h.z; }
    else if (S1 >= kr) { ci = 1; cg = S2;  Tl = h.y; }
    else               { ci = 0; cg = S1;  Tl = h.x; }
    const bool has = (S0 >= kr) && (inc < kr);    // exactly one lane true
    const unsigned long long m = __ballot(has);
    const int src = __ffsll((unsigned long long)m) - 1;
    chosen = __shfl((lane << 2) + ci, src, 64);
    cumG   = __shfl(cg, src, 64);
    T      = __shfl(Tl, src, 64);
}

__global__ void __launch_bounds__(512)
topk_mask_kernel(const float* __restrict__ x, const int* __restrict__ k0ptr,
                 float* __restrict__ out) {
    const int tid  = threadIdx.x;
    const int lane = tid & 63;
    const int w    = tid >> 6;                    // 0..7
    const int row  = blockIdx.x;

    const float4* xr4   = (const float4*)(x   + (size_t)row * DIM);
    float4*       outr4 = (float4*)      (out + (size_t)row * DIM);

    __shared__ int hist0[NC0 * CPAD];             // pass-0 replicas
    __shared__ int hist1[256];                    // pass 1
    __shared__ int histf[2][256];                 // fallback (lazily zeroed)
    __shared__ unsigned int surv[64];
    __shared__ int scnt;
    __shared__ int wtie[8];

    // ---- zero LDS FIRST: the upcoming barrier stays cheap (no vmcnt drain
    // of pending x loads, since none are issued yet).
    for (int t = tid; t < NC0 * CPAD; t += 512) hist0[t] = 0;
    if (tid < 256) hist1[tid] = 0;
    if (tid == 0) scnt = 0;
    __syncthreads();                              // zeros visible

    const int k0 = k0ptr[0];                      // uniform scalar load

    // ---- loads AFTER the barrier: each wave proceeds as ITS data arrives
    // (waves de-sync -> pass-0 atomic bursts spread in time).
    // Wave w owns elements [512w, 512w+512); elem of u[4i+c] (i in 0..1) is
    // 512w + 256i + 4*lane + c -> lexicographic (w,i,lane,c) = ascending idx.
    const nfloat4 f0 = nt_load4(&xr4[(w << 7) + lane]);
    const nfloat4 f1 = nt_load4(&xr4[(w << 7) + 64 + lane]);

    // fp32 -> sortable-ascending uint32 (registers, static indexing).
    unsigned int u[EPL];
#define MAP4(i, vv)                                                        \
    {                                                                      \
        unsigned int b0 = __float_as_uint((vv).x);                         \
        unsigned int b1 = __float_as_uint((vv).y);                         \
        unsigned int b2 = __float_as_uint((vv).z);                         \
        unsigned int b3 = __float_as_uint((vv).w);                         \
        u[4*(i)+0] = (b0 & 0x80000000u) ? ~b0 : (b0 | 0x80000000u);        \
        u[4*(i)+1] = (b1 & 0x80000000u) ? ~b1 : (b1 | 0x80000000u);        \
        u[4*(i)+2] = (b2 & 0x80000000u) ? ~b2 : (b2 | 0x80000000u);        \
        u[4*(i)+3] = (b3 & 0x80000000u) ? ~b3 : (b3 | 0x80000000u);        \
    }
    MAP4(0, f0) MAP4(1, f1)
#undef MAP4

    // ---- pass 0: replicated histogram of top byte (replica = lane&7) ----
    const int c0 = (lane & 7) * CPAD;
    #pragma unroll
    for (int j = 0; j < EPL; ++j)
        atomicAdd(&hist0[c0 + (u[j] >> 24)], 1);
    __syncthreads();

    int kr = k0;
    int4 h; h.x = 0; h.y = 0; h.z = 0; h.w = 0;
    #pragma unroll
    for (int c = 0; c < NC0; ++c) {
        const int4 t = *(const int4*)&hist0[c * CPAD + (lane << 2)];
        h.x += t.x; h.y += t.y; h.z += t.z; h.w += t.w;
    }
    int chosen, cumG, T;
    select_bin(h, lane, kr, chosen, cumG, T);
    kr -= cumG;
    unsigned int pfx = ((unsigned int)chosen) << 24;

    // ---- pass 1: byte 2 among survivors (sparse -> single copy) ----
    #pragma unroll
    for (int j = 0; j < EPL; ++j)
        if ((u[j] >> 24) == (pfx >> 24))
            atomicAdd(&hist1[(u[j] >> 16) & 255u], 1);
    __syncthreads();
    h = *(const int4*)&hist1[lane << 2];
    select_bin(h, lane, kr, chosen, cumG, T);
    kr -= cumG;
    pfx |= ((unsigned int)chosen) << 16;

    unsigned int thr;
    if (T <= 64) {
        // ---- common path: compact survivors, ballot bit-select low 16 bits --
        #pragma unroll
        for (int j = 0; j < EPL; ++j)
            if ((u[j] & 0xFFFF0000u) == pfx) {
                const int slot = atomicAdd(&scnt, 1);
                surv[slot] = u[j];
            }
        __syncthreads();
        // Every wave runs this redundantly on identical data -> no broadcast.
        const unsigned int v = (lane < T) ? surv[lane] : 0u;
        bool act = (lane < T);
        #pragma unroll
        for (int b = 15; b >= 0; --b) {
            const unsigned int bit = (v >> b) & 1u;
            const unsigned long long m1 = __ballot(act && (bit != 0u));
            const int c = __popcll(m1);
            const bool ge = (c >= kr);
            act = act && (bit == (ge ? 1u : 0u));
            if (!ge) kr -= c;
        }
        const unsigned long long ma = __ballot(act);
        T   = __popcll(ma);
        thr = __shfl(v, __ffsll((unsigned long long)ma) - 1, 64);
    } else {
        // ---- fallback (adversarial tie mass): zero lazily, then histogram
        // passes for bytes 1 and 0 ----
        ((int*)histf)[tid] = 0;                   // 512 ints, 512 threads
        __syncthreads();
        #pragma unroll
        for (int j = 0; j < EPL; ++j)
            if ((u[j] & 0xFFFF0000u) == pfx)
                atomicAdd(&histf[0][(u[j] >> 8) & 255u], 1);
        __syncthreads();
        h = *(const int4*)&histf[0][lane << 2];
        select_bin(h, lane, kr, chosen, cumG, T);
        kr -= cumG;
        pfx |= ((unsigned int)chosen) << 8;

        #pragma unroll
        for (int j = 0; j < EPL; ++j)
            if ((u[j] & 0xFFFFFF00u) == pfx)
                atomicAdd(&histf[1][u[j] & 255u], 1);
        __syncthreads();
        h = *(const int4*)&histf[1][lane << 2];
        select_bin(h, lane, kr, chosen, cumG, T);
        kr -= cumG;
        thr = pfx | (unsigned int)chosen;
    }
    // thr = k-th largest key; kr = ties to select; T = total ties (uniform).

    if (kr == T) {
        // All threshold ties selected: pure >= mask from registers.
        #pragma unroll
        for (int i = 0; i < 2; ++i) {
            float4 o;
            o.x = (u[4*i+0] >= thr) ? 1.0f : 0.0f;
            o.y = (u[4*i+1] >= thr) ? 1.0f : 0.0f;
            o.z = (u[4*i+2] >= thr) ? 1.0f : 0.0f;
            o.w = (u[4*i+3] >= thr) ? 1.0f : 0.0f;
            nt_store4(&outr4[(w << 7) + (i << 6) + lane], o);
        }
    } else {
        // Rare: rank exact ties in ascending global index order.
        int eqtot = 0;
        #pragma unroll
        for (int j = 0; j < EPL; ++j) eqtot += (u[j] == thr) ? 1 : 0;
        int vv = eqtot;
        #pragma unroll
        for (int off = 1; off < 64; off <<= 1) {
            int t = __shfl_up(vv, off, 64);
            if (lane >= off) vv += t;
        }
        if (lane == 63) wtie[w] = vv;             // per-wave tie totals
        __syncthreads();
        int base = 0;
        #pragma unroll
        for (int ww = 0; ww < 8; ++ww) if (ww < w) base += wtie[ww];

        #pragma unroll
        for (int i = 0; i < 2; ++i) {
            const int e0 = (u[4*i+0] == thr) ? 1 : 0;
            const int e1 = (u[4*i+1] == thr) ? 1 : 0;
            const int e2 = (u[4*i+2] == thr) ? 1 : 0;
            const int e3 = (u[4*i+3] == thr) ? 1 : 0;
            const int ti = e0 + e1 + e2 + e3;
            int vi = ti;
            #pragma unroll
            for (int off = 1; off < 64; off <<= 1) {
                int t = __shfl_up(vi, off, 64);
                if (lane >= off) vi += t;
            }
            int r = base + (vi - ti);             // ties before my first one
            const int tot = __shfl(vi, 63, 64);   // wave ties in this i-group
            float4 o;
            o.x = (u[4*i+0] > thr) ? 1.0f : ((e0 && r < kr) ? 1.0f : 0.0f); r += e0;
            o.y = (u[4*i+1] > thr) ? 1.0f : ((e1 && r < kr) ? 1.0f : 0.0f); r += e1;
            o.z = (u[4*i+2] > thr) ? 1.0f : ((e2 && r < kr) ? 1.0f : 0.0f); r += e2;
            o.w = (u[4*i+3] > thr) ? 1.0f : ((e3 && r < kr) ? 1.0f : 0.0f); r += e3;
            nt_store4(&outr4[(w << 7) + (i << 6) + lane], o);
            base += tot;
        }
    }
}

extern "C" void kernel_launch(void* const* d_in, const int* in_sizes, int n_in,
                              void* d_out, int out_size, void* d_ws, size_t ws_size,
                              hipStream_t stream) {
    const float* x   = (const float*)d_in[0];
    // d_in[1] = k vector [bs] (unused: forward mask depends only on k0)
    const int*   k0  = (const int*)d_in[2];
    float*       out = (float*)d_out;

    const int bs = in_sizes[1];                   // dim == 4096 (reference)
    topk_mask_kernel<<<bs, 512, 0, stream>>>(x, k0, out);
}